// Round 1
// baseline (366.202 us; speedup 1.0000x reference)
//
#include <hip/hip_runtime.h>

typedef __attribute__((ext_vector_type(8))) short bf16x8;
typedef __attribute__((ext_vector_type(4))) short bf16x4;
typedef __attribute__((ext_vector_type(4))) float f32x4;

#define H_BS 8
#define H_L 1024
#define H_S 1024
#define H_E 768
#define H_NH 12
#define H_HD 64

static __device__ __forceinline__ short f2bf(float f) {
  union { float f; unsigned u; } v; v.f = f;
  unsigned r = v.u + 0x7fffu + ((v.u >> 16) & 1u);
  return (short)(r >> 16);
}

// C[M,N] = A[M,768] @ W[N,768]^T + bias, M=8192, N=768, tile 128x128x32.
// OUT_MODE: 0 = fp32 [M,N] (d_out), 1 = bf16 q [B,H,L,D] *0.125,
//           2 = bf16 k [B,H,S,D], 3 = bf16 v^T [B,H,D,S]
template<int OUT_MODE, bool A_BF16>
__global__ __launch_bounds__(256)
void smha_gemm(const void* __restrict__ Aptr, const float* __restrict__ W,
               const float* __restrict__ bias, void* __restrict__ outp)
{
  __shared__ short a_s[128][40];   // +8 pad: 80B stride -> 2-way bank alias (free)
  __shared__ short w_s[128][40];

  const int m0 = blockIdx.y * 128;
  const int n0 = blockIdx.x * 128;
  const int t = threadIdx.x;
  const int lane = t & 63;
  const int wv = t >> 6;          // wave 0..3 (2x2 over 64x64 sub-tiles)
  const int wm = (wv >> 1) * 64;
  const int wn = (wv & 1) * 64;
  const int lr = lane & 15;
  const int lg = lane >> 4;       // 0..3

  f32x4 acc[4][4];
  const f32x4 zero = {0.f, 0.f, 0.f, 0.f};
  #pragma unroll
  for (int i = 0; i < 4; ++i)
    #pragma unroll
    for (int j = 0; j < 4; ++j)
      acc[i][j] = zero;

  const int trow = t >> 3;        // 0..31
  const int tcol = (t & 7) * 4;   // 0..28

  for (int kt = 0; kt < H_E / 32; ++kt) {
    const int k0 = kt * 32;
    __syncthreads();
    // stage W tile [128 n][32 k], fp32 -> bf16
    #pragma unroll
    for (int r = 0; r < 4; ++r) {
      const int row = trow + r * 32;
      const float4 wvv = *reinterpret_cast<const float4*>(&W[(size_t)(n0 + row) * H_E + k0 + tcol]);
      bf16x4 s4;
      s4[0] = f2bf(wvv.x); s4[1] = f2bf(wvv.y); s4[2] = f2bf(wvv.z); s4[3] = f2bf(wvv.w);
      *reinterpret_cast<bf16x4*>(&w_s[row][tcol]) = s4;
    }
    // stage A tile [128 m][32 k]
    if (A_BF16) {
      const short* Ab = (const short*)Aptr;
      const int row = t >> 1;
      const int c = (t & 1) * 16;
      *reinterpret_cast<bf16x8*>(&a_s[row][c]) =
          *reinterpret_cast<const bf16x8*>(&Ab[(size_t)(m0 + row) * H_E + k0 + c]);
      *reinterpret_cast<bf16x8*>(&a_s[row][c + 8]) =
          *reinterpret_cast<const bf16x8*>(&Ab[(size_t)(m0 + row) * H_E + k0 + c + 8]);
    } else {
      const float* Af = (const float*)Aptr;
      #pragma unroll
      for (int r = 0; r < 4; ++r) {
        const int row = trow + r * 32;
        const float4 av = *reinterpret_cast<const float4*>(&Af[(size_t)(m0 + row) * H_E + k0 + tcol]);
        bf16x4 s4;
        s4[0] = f2bf(av.x); s4[1] = f2bf(av.y); s4[2] = f2bf(av.z); s4[3] = f2bf(av.w);
        *reinterpret_cast<bf16x4*>(&a_s[row][tcol]) = s4;
      }
    }
    __syncthreads();

    bf16x8 af[4], bfr[4];
    #pragma unroll
    for (int i = 0; i < 4; ++i)
      af[i] = *reinterpret_cast<const bf16x8*>(&a_s[wm + i * 16 + lr][lg * 8]);
    #pragma unroll
    for (int i = 0; i < 4; ++i)
      bfr[i] = *reinterpret_cast<const bf16x8*>(&w_s[wn + i * 16 + lr][lg * 8]);
    #pragma unroll
    for (int i = 0; i < 4; ++i)
      #pragma unroll
      for (int j = 0; j < 4; ++j)
        acc[i][j] = __builtin_amdgcn_mfma_f32_16x16x32_bf16(af[i], bfr[j], acc[i][j], 0, 0, 0);
  }

  // epilogue: D layout col = lane&15, row = (lane>>4)*4 + e
  #pragma unroll
  for (int j = 0; j < 4; ++j) {
    const int gn = n0 + wn + j * 16 + lr;
    const float bv = bias[gn];
    #pragma unroll
    for (int i = 0; i < 4; ++i) {
      #pragma unroll
      for (int e = 0; e < 4; ++e) {
        const int gm = m0 + wm + i * 16 + lg * 4 + e;
        const float val = acc[i][j][e] + bv;
        if (OUT_MODE == 0) {
          ((float*)outp)[(size_t)gm * H_E + gn] = val;
        } else {
          const int bb = gm >> 10, ll = gm & 1023;
          const int hh = gn >> 6, dd = gn & 63;
          short* o16 = (short*)outp;
          if (OUT_MODE == 1)
            o16[((size_t)(bb * H_NH + hh) * H_L + ll) * H_HD + dd] = f2bf(val * 0.125f);
          else if (OUT_MODE == 2)
            o16[((size_t)(bb * H_NH + hh) * H_S + ll) * H_HD + dd] = f2bf(val);
          else
            o16[((size_t)(bb * H_NH + hh) * H_HD + dd) * H_S + ll] = f2bf(val);
        }
      }
    }
  }
}

// Flash attention: block = (b, h, 64-row q tile); 4 waves x 16 q-rows.
// q [B,H,L,D] bf16 (pre-scaled), k [B,H,S,D] bf16, vt [B,H,D,S] bf16.
// out: bf16 [B, L, E] (head-concat) for the final projection.
__global__ __launch_bounds__(256)
void smha_attn(const short* __restrict__ q, const short* __restrict__ k,
               const short* __restrict__ vt, const float* __restrict__ kpm,
               const float* __restrict__ sf, short* __restrict__ outp)
{
  __shared__ short k_s[64][72];      // [s][d], 144B stride -> 2-way alias (free)
  __shared__ short v_s[64][72];      // [d][s]
  __shared__ short p_s[4][16][72];   // per-wave P tile [q][s]

  const int blk = blockIdx.x;
  const int qt = blk & 15;
  const int hh = (blk >> 4) % H_NH;
  const int bb = blk / (16 * H_NH);
  const int bh = bb * H_NH + hh;
  const int t = threadIdx.x;
  const int wv = t >> 6;
  const int lane = t & 63;
  const int lr = lane & 15;
  const int lg = lane >> 4;

  const int q0 = qt * 64 + wv * 16;

  // Q fragments (A operand): row = lane&15, k-slice = lg*8 (+32 per frag)
  bf16x8 qf[2];
  #pragma unroll
  for (int kk = 0; kk < 2; ++kk)
    qf[kk] = *reinterpret_cast<const bf16x8*>(
        &q[((size_t)bh * H_L + q0 + lr) * H_HD + kk * 32 + lg * 8]);

  const float sfh = sf[hh];

  f32x4 o_acc[4];
  const f32x4 zero = {0.f, 0.f, 0.f, 0.f};
  #pragma unroll
  for (int di = 0; di < 4; ++di) o_acc[di] = zero;
  float mrow[4], lrow[4];
  #pragma unroll
  for (int j = 0; j < 4; ++j) { mrow[j] = -1e30f; lrow[j] = 0.f; }

  const int srow = t >> 2;          // 0..63
  const int scol = (t & 3) * 16;    // 0,16,32,48

  for (int kv = 0; kv < H_S / 64; ++kv) {
    const int s0 = kv * 64;
    __syncthreads();
    // stage K [64 s][64 d] and V^T [64 d][64 s]
    *reinterpret_cast<bf16x8*>(&k_s[srow][scol]) =
        *reinterpret_cast<const bf16x8*>(&k[((size_t)bh * H_S + s0 + srow) * H_HD + scol]);
    *reinterpret_cast<bf16x8*>(&k_s[srow][scol + 8]) =
        *reinterpret_cast<const bf16x8*>(&k[((size_t)bh * H_S + s0 + srow) * H_HD + scol + 8]);
    *reinterpret_cast<bf16x8*>(&v_s[srow][scol]) =
        *reinterpret_cast<const bf16x8*>(&vt[((size_t)bh * H_HD + srow) * H_S + s0 + scol]);
    *reinterpret_cast<bf16x8*>(&v_s[srow][scol + 8]) =
        *reinterpret_cast<const bf16x8*>(&vt[((size_t)bh * H_HD + srow) * H_S + s0 + scol + 8]);
    __syncthreads();

    // scores S = Q K^T : [16 q][64 s]
    f32x4 sc[4];
    #pragma unroll
    for (int ni = 0; ni < 4; ++ni) sc[ni] = zero;
    #pragma unroll
    for (int kk = 0; kk < 2; ++kk) {
      #pragma unroll
      for (int ni = 0; ni < 4; ++ni) {
        const bf16x8 bfr = *reinterpret_cast<const bf16x8*>(&k_s[ni * 16 + lr][kk * 32 + lg * 8]);
        sc[ni] = __builtin_amdgcn_mfma_f32_16x16x32_bf16(qf[kk], bfr, sc[ni], 0, 0, 0);
      }
    }

    // soft key-padding bias (depends only on s column)
    float bias_c[4];
    #pragma unroll
    for (int ni = 0; ni < 4; ++ni)
      bias_c[ni] = kpm[bb * H_S + s0 + ni * 16 + lr] * sfh;

    // online softmax; lane holds rows (lg*4+j), cols ni*16+lr
    #pragma unroll
    for (int j = 0; j < 4; ++j) {
      float mx = -1e30f;
      #pragma unroll
      for (int ni = 0; ni < 4; ++ni) {
        sc[ni][j] += bias_c[ni];
        mx = fmaxf(mx, sc[ni][j]);
      }
      mx = fmaxf(mx, __shfl_xor(mx, 1));
      mx = fmaxf(mx, __shfl_xor(mx, 2));
      mx = fmaxf(mx, __shfl_xor(mx, 4));
      mx = fmaxf(mx, __shfl_xor(mx, 8));
      const float mnew = fmaxf(mrow[j], mx);
      const float scale = __expf(mrow[j] - mnew);
      float rsum = 0.f;
      #pragma unroll
      for (int ni = 0; ni < 4; ++ni) {
        const float p = __expf(sc[ni][j] - mnew);
        sc[ni][j] = p;
        rsum += p;
      }
      rsum += __shfl_xor(rsum, 1);
      rsum += __shfl_xor(rsum, 2);
      rsum += __shfl_xor(rsum, 4);
      rsum += __shfl_xor(rsum, 8);
      lrow[j] = lrow[j] * scale + rsum;
      mrow[j] = mnew;
      #pragma unroll
      for (int di = 0; di < 4; ++di) o_acc[di][j] *= scale;
    }

    // P -> bf16 -> per-wave LDS (to reach A-fragment layout)
    #pragma unroll
    for (int ni = 0; ni < 4; ++ni)
      #pragma unroll
      for (int j = 0; j < 4; ++j)
        p_s[wv][lg * 4 + j][ni * 16 + lr] = f2bf(sc[ni][j]);

    // O += P V : contraction over s (2 slices of 32)
    #pragma unroll
    for (int kk = 0; kk < 2; ++kk) {
      const bf16x8 pf = *reinterpret_cast<const bf16x8*>(&p_s[wv][lr][kk * 32 + lg * 8]);
      #pragma unroll
      for (int di = 0; di < 4; ++di) {
        const bf16x8 vfr = *reinterpret_cast<const bf16x8*>(&v_s[di * 16 + lr][kk * 32 + lg * 8]);
        o_acc[di] = __builtin_amdgcn_mfma_f32_16x16x32_bf16(pf, vfr, o_acc[di], 0, 0, 0);
      }
    }
  }

  // epilogue: normalize and write bf16 [B, L, E]
  #pragma unroll
  for (int j = 0; j < 4; ++j) {
    const float rl = 1.0f / lrow[j];
    const int gq = q0 + lg * 4 + j;
    #pragma unroll
    for (int di = 0; di < 4; ++di)
      outp[((size_t)bb * H_L + gq) * H_E + hh * H_HD + di * 16 + lr] =
          f2bf(o_acc[di][j] * rl);
  }
}

extern "C" void kernel_launch(void* const* d_in, const int* in_sizes, int n_in,
                              void* d_out, int out_size, void* d_ws, size_t ws_size,
                              hipStream_t stream)
{
  // inputs: 0 query, 1 key, 2 value, 3 kpm, 4 Wq, 5 bq, 6 Wk, 7 bk,
  //         8 Wv, 9 bv, 10 Wo, 11 bo, 12 scaling_factors
  const size_t qkv = (size_t)H_BS * H_NH * H_L * H_HD;  // 6.29M elems
  short* ws_q    = (short*)d_ws;
  short* ws_k    = ws_q + qkv;
  short* ws_vt   = ws_k + qkv;
  short* ws_attn = ws_vt + qkv;

  dim3 grid(H_E / 128, (H_BS * H_L) / 128);  // (6, 64)
  smha_gemm<1, false><<<grid, 256, 0, stream>>>(d_in[0], (const float*)d_in[4], (const float*)d_in[5], ws_q);
  smha_gemm<2, false><<<grid, 256, 0, stream>>>(d_in[1], (const float*)d_in[6], (const float*)d_in[7], ws_k);
  smha_gemm<3, false><<<grid, 256, 0, stream>>>(d_in[2], (const float*)d_in[8], (const float*)d_in[9], ws_vt);

  smha_attn<<<H_BS * H_NH * (H_L / 64), 256, 0, stream>>>(
      ws_q, ws_k, ws_vt, (const float*)d_in[3], (const float*)d_in[12], ws_attn);

  smha_gemm<0, true><<<grid, 256, 0, stream>>>(ws_attn, (const float*)d_in[10], (const float*)d_in[11], d_out);
}

// Round 2
// 332.141 us; speedup vs baseline: 1.1026x; 1.1026x over previous
//
#include <hip/hip_runtime.h>
#include <hip/hip_bf16.h>

typedef __attribute__((ext_vector_type(8))) short bf16x8;
typedef __attribute__((ext_vector_type(4))) float f32x4;

#define H_BS 8
#define H_L 1024
#define H_S 1024
#define H_E 768
#define H_NH 12
#define H_HD 64
#define EE (H_E * H_E)

static __device__ __forceinline__ short cvtbf(float f) {
  __hip_bfloat16 h = __float2bfloat16(f);
  return *reinterpret_cast<short*>(&h);
}

static __device__ __forceinline__ void gload16(const void* g, void* l) {
  __builtin_amdgcn_global_load_lds(
      (const __attribute__((address_space(1))) void*)g,
      (__attribute__((address_space(3))) void*)l, 16, 0, 0);
}

// Convert the 4 weight matrices (768x768 fp32) to bf16. grid (EE/2048, 4).
__global__ __launch_bounds__(256)
void conv_w4(const float* __restrict__ w0, const float* __restrict__ w1,
             const float* __restrict__ w2, const float* __restrict__ w3,
             short* __restrict__ out)
{
  const int y = blockIdx.y;
  const float* in = (y == 0) ? w0 : (y == 1) ? w1 : (y == 2) ? w2 : w3;
  short* o = out + (size_t)y * EE;
  const int i = (blockIdx.x * 256 + threadIdx.x) * 8;
  const float4 f0 = *reinterpret_cast<const float4*>(in + i);
  const float4 f1 = *reinterpret_cast<const float4*>(in + i + 4);
  bf16x8 r;
  r[0] = cvtbf(f0.x); r[1] = cvtbf(f0.y); r[2] = cvtbf(f0.z); r[3] = cvtbf(f0.w);
  r[4] = cvtbf(f1.x); r[5] = cvtbf(f1.y); r[6] = cvtbf(f1.z); r[7] = cvtbf(f1.w);
  *reinterpret_cast<bf16x8*>(o + i) = r;
}

// Fused Q/K/V projection GEMM. C[M,N] = A[M,768] @ W[N,768]^T + b.
// Tile 64x128x32, 4 waves (2x2 over 32x64 sub-tiles). blockIdx.z = 0/1/2 -> q/k/v.
// A fp32 reg-staged (cvt to bf16); W bf16 via global_load_lds (linear LDS).
__global__ __launch_bounds__(256)
void qkv_gemm(const float* __restrict__ Aq, const float* __restrict__ Ak,
              const float* __restrict__ Av, const short* __restrict__ Wbf,
              const float* __restrict__ bq, const float* __restrict__ bk,
              const float* __restrict__ bv, short* __restrict__ oq,
              short* __restrict__ ok_, short* __restrict__ ov)
{
  __shared__ short a_s[64][32];
  __shared__ short w_s[128][32];

  const int mode = blockIdx.z;
  const float* A    = (mode == 0) ? Aq : (mode == 1) ? Ak : Av;
  const short* W    = Wbf + (size_t)mode * EE;
  const float* bias = (mode == 0) ? bq : (mode == 1) ? bk : bv;

  const int m0 = blockIdx.y * 64;
  const int n0 = blockIdx.x * 128;
  const int t = threadIdx.x;
  const int lane = t & 63;
  const int wv = t >> 6;
  const int wm = (wv >> 1) * 32;
  const int wn = (wv & 1) * 64;
  const int lr = lane & 15;
  const int lg = lane >> 4;

  f32x4 acc[2][4];
  const f32x4 zero = {0.f, 0.f, 0.f, 0.f};
  #pragma unroll
  for (int i = 0; i < 2; ++i)
    #pragma unroll
    for (int j = 0; j < 4; ++j) acc[i][j] = zero;

  // A staging coords (fp32 -> regs -> bf16 -> LDS)
  const int arow = t >> 2;
  const int acol = (t & 3) * 8;
  const float* aptr = A + (size_t)(m0 + arow) * H_E + acol;

  // W gload coords: instr (wv, i) covers rows (wv*2+i)*16, lane -> row +(l>>2), col (l&3)*8
  const int wrow = wv * 32 + (lane >> 2);
  const int wcol = (lane & 3) * 8;
  const short* wptr0 = W + (size_t)(n0 + wrow) * H_E + wcol;
  const short* wptr1 = W + (size_t)(n0 + wrow + 16) * H_E + wcol;
  short* wdst0 = &w_s[0][0] + wv * 1024;   // (wv*2)*512 shorts
  short* wdst1 = wdst0 + 512;

  float4 a0 = *reinterpret_cast<const float4*>(aptr);
  float4 a1 = *reinterpret_cast<const float4*>(aptr + 4);

  for (int kt = 0; kt < H_E / 32; ++kt) {
    __syncthreads();
    bf16x8 avv;
    avv[0] = cvtbf(a0.x); avv[1] = cvtbf(a0.y); avv[2] = cvtbf(a0.z); avv[3] = cvtbf(a0.w);
    avv[4] = cvtbf(a1.x); avv[5] = cvtbf(a1.y); avv[6] = cvtbf(a1.z); avv[7] = cvtbf(a1.w);
    *reinterpret_cast<bf16x8*>(&a_s[arow][acol]) = avv;
    gload16(wptr0 + kt * 32, wdst0);
    gload16(wptr1 + kt * 32, wdst1);
    __syncthreads();
    if (kt < H_E / 32 - 1) {
      a0 = *reinterpret_cast<const float4*>(aptr + (kt + 1) * 32);
      a1 = *reinterpret_cast<const float4*>(aptr + (kt + 1) * 32 + 4);
    }
    bf16x8 af[2], wf[4];
    #pragma unroll
    for (int i = 0; i < 2; ++i)
      af[i] = *reinterpret_cast<const bf16x8*>(&a_s[wm + i * 16 + lr][lg * 8]);
    #pragma unroll
    for (int j = 0; j < 4; ++j)
      wf[j] = *reinterpret_cast<const bf16x8*>(&w_s[wn + j * 16 + lr][lg * 8]);
    #pragma unroll
    for (int i = 0; i < 2; ++i)
      #pragma unroll
      for (int j = 0; j < 4; ++j)
        acc[i][j] = __builtin_amdgcn_mfma_f32_16x16x32_bf16(af[i], wf[j], acc[i][j], 0, 0, 0);
  }

  #pragma unroll
  for (int j = 0; j < 4; ++j) {
    const int gn = n0 + wn + j * 16 + lr;
    const float bvl = bias[gn];
    const int hh = gn >> 6, dd = gn & 63;
    #pragma unroll
    for (int i = 0; i < 2; ++i) {
      #pragma unroll
      for (int e = 0; e < 4; ++e) {
        const int gm = m0 + wm + i * 16 + lg * 4 + e;
        const float val = acc[i][j][e] + bvl;
        const int bb = gm >> 10, ll = gm & 1023;
        if (mode == 0)
          oq[((size_t)(bb * H_NH + hh) * H_L + ll) * H_HD + dd] = cvtbf(val * 0.125f);
        else if (mode == 1)
          ok_[((size_t)(bb * H_NH + hh) * H_S + ll) * H_HD + dd] = cvtbf(val);
        else
          ov[((size_t)(bb * H_NH + hh) * H_HD + dd) * H_S + ll] = cvtbf(val);
      }
    }
  }
}

// Output projection: C[M,768] = A_bf16[M,768] @ Wo[768,768]^T + bo -> fp32 d_out.
// Both A and W staged via global_load_lds.
__global__ __launch_bounds__(256)
void out_gemm(const short* __restrict__ A, const short* __restrict__ W,
              const float* __restrict__ bias, float* __restrict__ outp)
{
  __shared__ short a_s[64][32];
  __shared__ short w_s[128][32];

  const int m0 = blockIdx.y * 64;
  const int n0 = blockIdx.x * 128;
  const int t = threadIdx.x;
  const int lane = t & 63;
  const int wv = t >> 6;
  const int wm = (wv >> 1) * 32;
  const int wn = (wv & 1) * 64;
  const int lr = lane & 15;
  const int lg = lane >> 4;

  f32x4 acc[2][4];
  const f32x4 zero = {0.f, 0.f, 0.f, 0.f};
  #pragma unroll
  for (int i = 0; i < 2; ++i)
    #pragma unroll
    for (int j = 0; j < 4; ++j) acc[i][j] = zero;

  const int grow = wv * 16 + (lane >> 2);
  const int gcol = (lane & 3) * 8;
  const short* aptr = A + (size_t)(m0 + grow) * H_E + gcol;
  short* adst = &a_s[0][0] + wv * 512;

  const int wrow = wv * 32 + (lane >> 2);
  const short* wptr0 = W + (size_t)(n0 + wrow) * H_E + gcol;
  const short* wptr1 = W + (size_t)(n0 + wrow + 16) * H_E + gcol;
  short* wdst0 = &w_s[0][0] + wv * 1024;
  short* wdst1 = wdst0 + 512;

  for (int kt = 0; kt < H_E / 32; ++kt) {
    __syncthreads();
    gload16(aptr + kt * 32, adst);
    gload16(wptr0 + kt * 32, wdst0);
    gload16(wptr1 + kt * 32, wdst1);
    __syncthreads();
    bf16x8 af[2], wf[4];
    #pragma unroll
    for (int i = 0; i < 2; ++i)
      af[i] = *reinterpret_cast<const bf16x8*>(&a_s[wm + i * 16 + lr][lg * 8]);
    #pragma unroll
    for (int j = 0; j < 4; ++j)
      wf[j] = *reinterpret_cast<const bf16x8*>(&w_s[wn + j * 16 + lr][lg * 8]);
    #pragma unroll
    for (int i = 0; i < 2; ++i)
      #pragma unroll
      for (int j = 0; j < 4; ++j)
        acc[i][j] = __builtin_amdgcn_mfma_f32_16x16x32_bf16(af[i], wf[j], acc[i][j], 0, 0, 0);
  }

  #pragma unroll
  for (int j = 0; j < 4; ++j) {
    const int gn = n0 + wn + j * 16 + lr;
    const float bvl = bias[gn];
    #pragma unroll
    for (int i = 0; i < 2; ++i) {
      #pragma unroll
      for (int e = 0; e < 4; ++e) {
        const int gm = m0 + wm + i * 16 + lg * 4 + e;
        outp[(size_t)gm * H_E + gn] = acc[i][j][e] + bvl;
      }
    }
  }
}

// Flash attention: block = (b, h, 64-row q tile); 4 waves x 16 q-rows.
__global__ __launch_bounds__(256)
void smha_attn(const short* __restrict__ q, const short* __restrict__ k,
               const short* __restrict__ vt, const float* __restrict__ kpm,
               const float* __restrict__ sf, short* __restrict__ outp)
{
  __shared__ short k_s[64][72];      // padded: 144B stride (slot spread optimal)
  __shared__ short v_s[64][72];
  __shared__ short p_s[4][16][72];

  const int blk = blockIdx.x;
  const int qt = blk & 15;
  const int hh = (blk >> 4) % H_NH;
  const int bb = blk / (16 * H_NH);
  const int bh = bb * H_NH + hh;
  const int t = threadIdx.x;
  const int wv = t >> 6;
  const int lane = t & 63;
  const int lr = lane & 15;
  const int lg = lane >> 4;

  const int q0 = qt * 64 + wv * 16;

  bf16x8 qf[2];
  #pragma unroll
  for (int kk = 0; kk < 2; ++kk)
    qf[kk] = *reinterpret_cast<const bf16x8*>(
        &q[((size_t)bh * H_L + q0 + lr) * H_HD + kk * 32 + lg * 8]);

  const float sfh = sf[hh];

  f32x4 o_acc[4];
  const f32x4 zero = {0.f, 0.f, 0.f, 0.f};
  #pragma unroll
  for (int di = 0; di < 4; ++di) o_acc[di] = zero;
  float mrow[4], lrow[4];
  #pragma unroll
  for (int j = 0; j < 4; ++j) { mrow[j] = -1e30f; lrow[j] = 0.f; }

  const int srow = t >> 2;
  const int scol = (t & 3) * 16;

  // T14: preload tile 0 into regs; in-loop, issue tile kv+1 loads after barrier2
  const short* kp = &k[((size_t)bh * H_S + srow) * H_HD + scol];
  const short* vp = &vt[((size_t)bh * H_HD + srow) * H_S + scol];
  bf16x8 kr0 = *reinterpret_cast<const bf16x8*>(kp);
  bf16x8 kr1 = *reinterpret_cast<const bf16x8*>(kp + 8);
  bf16x8 vr0 = *reinterpret_cast<const bf16x8*>(vp);
  bf16x8 vr1 = *reinterpret_cast<const bf16x8*>(vp + 8);

  for (int kv = 0; kv < H_S / 64; ++kv) {
    const int s0 = kv * 64;
    __syncthreads();
    *reinterpret_cast<bf16x8*>(&k_s[srow][scol])     = kr0;
    *reinterpret_cast<bf16x8*>(&k_s[srow][scol + 8]) = kr1;
    *reinterpret_cast<bf16x8*>(&v_s[srow][scol])     = vr0;
    *reinterpret_cast<bf16x8*>(&v_s[srow][scol + 8]) = vr1;
    __syncthreads();
    if (kv + 1 < H_S / 64) {
      const short* kpn = kp + (size_t)(kv + 1) * 64 * H_HD;
      const short* vpn = vp + (size_t)(kv + 1) * 64;
      kr0 = *reinterpret_cast<const bf16x8*>(kpn);
      kr1 = *reinterpret_cast<const bf16x8*>(kpn + 8);
      vr0 = *reinterpret_cast<const bf16x8*>(vpn);
      vr1 = *reinterpret_cast<const bf16x8*>(vpn + 8);
    }

    float bias_c[4];
    #pragma unroll
    for (int ni = 0; ni < 4; ++ni)
      bias_c[ni] = kpm[bb * H_S + s0 + ni * 16 + lr] * sfh;

    // S = Q K^T : [16 q][64 s]
    f32x4 sc[4];
    #pragma unroll
    for (int ni = 0; ni < 4; ++ni) sc[ni] = zero;
    #pragma unroll
    for (int kk = 0; kk < 2; ++kk) {
      #pragma unroll
      for (int ni = 0; ni < 4; ++ni) {
        const bf16x8 bfr = *reinterpret_cast<const bf16x8*>(&k_s[ni * 16 + lr][kk * 32 + lg * 8]);
        sc[ni] = __builtin_amdgcn_mfma_f32_16x16x32_bf16(qf[kk], bfr, sc[ni], 0, 0, 0);
      }
    }

    // online softmax with T13 defer-rescale (THR=8)
    #pragma unroll
    for (int j = 0; j < 4; ++j) {
      float mx = -1e30f;
      #pragma unroll
      for (int ni = 0; ni < 4; ++ni) {
        sc[ni][j] += bias_c[ni];
        mx = fmaxf(mx, sc[ni][j]);
      }
      mx = fmaxf(mx, __shfl_xor(mx, 1));
      mx = fmaxf(mx, __shfl_xor(mx, 2));
      mx = fmaxf(mx, __shfl_xor(mx, 4));
      mx = fmaxf(mx, __shfl_xor(mx, 8));
      if (!__all(mx <= mrow[j] + 8.0f)) {
        const float mnew = fmaxf(mrow[j], mx);
        const float scal = __expf(mrow[j] - mnew);
        lrow[j] *= scal;
        #pragma unroll
        for (int di = 0; di < 4; ++di) o_acc[di][j] *= scal;
        mrow[j] = mnew;
      }
      float rsum = 0.f;
      #pragma unroll
      for (int ni = 0; ni < 4; ++ni) {
        const float p = __expf(sc[ni][j] - mrow[j]);
        sc[ni][j] = p;
        rsum += p;
      }
      rsum += __shfl_xor(rsum, 1);
      rsum += __shfl_xor(rsum, 2);
      rsum += __shfl_xor(rsum, 4);
      rsum += __shfl_xor(rsum, 8);
      lrow[j] += rsum;
    }

    // P -> bf16 -> per-wave LDS
    #pragma unroll
    for (int ni = 0; ni < 4; ++ni)
      #pragma unroll
      for (int j = 0; j < 4; ++j)
        p_s[wv][lg * 4 + j][ni * 16 + lr] = cvtbf(sc[ni][j]);

    // O += P V
    #pragma unroll
    for (int kk = 0; kk < 2; ++kk) {
      const bf16x8 pf = *reinterpret_cast<const bf16x8*>(&p_s[wv][lr][kk * 32 + lg * 8]);
      #pragma unroll
      for (int di = 0; di < 4; ++di) {
        const bf16x8 vfr = *reinterpret_cast<const bf16x8*>(&v_s[di * 16 + lr][kk * 32 + lg * 8]);
        o_acc[di] = __builtin_amdgcn_mfma_f32_16x16x32_bf16(pf, vfr, o_acc[di], 0, 0, 0);
      }
    }
  }

  #pragma unroll
  for (int j = 0; j < 4; ++j) {
    const float rl = 1.0f / lrow[j];
    const int gq = q0 + lg * 4 + j;
    #pragma unroll
    for (int di = 0; di < 4; ++di)
      outp[((size_t)bb * H_L + gq) * H_E + hh * H_HD + di * 16 + lr] =
          cvtbf(o_acc[di][j] * rl);
  }
}

extern "C" void kernel_launch(void* const* d_in, const int* in_sizes, int n_in,
                              void* d_out, int out_size, void* d_ws, size_t ws_size,
                              hipStream_t stream)
{
  // 0 query, 1 key, 2 value, 3 kpm, 4 Wq, 5 bq, 6 Wk, 7 bk, 8 Wv, 9 bv,
  // 10 Wo, 11 bo, 12 scaling_factors
  const size_t qkv = (size_t)H_BS * H_NH * H_L * H_HD;  // 6291456
  short* ws_w  = (short*)d_ws;            // 4*EE bf16 weights (Wq,Wk,Wv,Wo)
  short* ws_q  = ws_w + (size_t)4 * EE;
  short* ws_k  = ws_q + qkv;
  short* ws_vt = ws_k + qkv;
  short* ws_at = ws_vt + qkv;             // total ~55 MB

  conv_w4<<<dim3(EE / 2048, 4), 256, 0, stream>>>(
      (const float*)d_in[4], (const float*)d_in[6], (const float*)d_in[8],
      (const float*)d_in[10], ws_w);

  qkv_gemm<<<dim3(H_E / 128, (H_BS * H_L) / 64, 3), 256, 0, stream>>>(
      (const float*)d_in[0], (const float*)d_in[1], (const float*)d_in[2],
      ws_w, (const float*)d_in[5], (const float*)d_in[7], (const float*)d_in[9],
      ws_q, ws_k, ws_vt);

  smha_attn<<<H_BS * H_NH * (H_L / 64), 256, 0, stream>>>(
      ws_q, ws_k, ws_vt, (const float*)d_in[3], (const float*)d_in[12], ws_at);

  out_gemm<<<dim3(H_E / 128, (H_BS * H_L) / 64), 256, 0, stream>>>(
      ws_at, ws_w + (size_t)3 * EE, (const float*)d_in[11], (float*)d_out);
}

// Round 3
// 319.314 us; speedup vs baseline: 1.1468x; 1.0402x over previous
//
#include <hip/hip_runtime.h>
#include <hip/hip_bf16.h>

typedef __attribute__((ext_vector_type(8))) short bf16x8;
typedef __attribute__((ext_vector_type(4))) float f32x4;

#define H_BS 8
#define H_L 1024
#define H_S 1024
#define H_E 768
#define H_NH 12
#define H_HD 64
#define EE (H_E * H_E)                 // 589824
#define AN (H_BS * H_L * H_E)          // 6291456

static __device__ __forceinline__ short cvtbf(float f) {
  __hip_bfloat16 h = __float2bfloat16(f);
  return *reinterpret_cast<short*>(&h);
}

static __device__ __forceinline__ void gload16(const void* g, void* l) {
  __builtin_amdgcn_global_load_lds(
      (const __attribute__((address_space(1))) void*)g,
      (__attribute__((address_space(3))) void*)l, 16, 0, 0);
}

// fp32 -> bf16 for 4 weight matrices + 3 activation tensors.
// grid (AN/2048, 7); y<4 -> weights (EE), y>=4 -> activations (AN).
__global__ __launch_bounds__(256)
void conv_bf16(const float* __restrict__ w0, const float* __restrict__ w1,
               const float* __restrict__ w2, const float* __restrict__ w3,
               const float* __restrict__ a0, const float* __restrict__ a1,
               const float* __restrict__ a2,
               short* __restrict__ ws_w, short* __restrict__ ws_a)
{
  const int y = blockIdx.y;
  const float* src;
  short* dst;
  int n;
  if (y < 4) {
    src = (y == 0) ? w0 : (y == 1) ? w1 : (y == 2) ? w2 : w3;
    dst = ws_w + (size_t)y * EE;
    n = EE;
  } else {
    src = (y == 4) ? a0 : (y == 5) ? a1 : a2;
    dst = ws_a + (size_t)(y - 4) * AN;
    n = AN;
  }
  const int i = (blockIdx.x * 256 + threadIdx.x) * 8;
  if (i >= n) return;
  const float4 f0 = *reinterpret_cast<const float4*>(src + i);
  const float4 f1 = *reinterpret_cast<const float4*>(src + i + 4);
  bf16x8 r;
  r[0] = cvtbf(f0.x); r[1] = cvtbf(f0.y); r[2] = cvtbf(f0.z); r[3] = cvtbf(f0.w);
  r[4] = cvtbf(f1.x); r[5] = cvtbf(f1.y); r[6] = cvtbf(f1.z); r[7] = cvtbf(f1.w);
  *reinterpret_cast<bf16x8*>(dst + i) = r;
}

// m97-structure GEMM: C[M,N] = A[M,768] @ W[N,768]^T + b, tile 128x128x32,
// 4 waves (2x2 over 64x64), all-bf16, global_load_lds staging, 2-barrier loop.
// Fused QKV: blockIdx.z = mode (0 q, 1 k, 2 v^T), scatter epilogue.
__global__ __launch_bounds__(256)
void qkv_gemm(const short* __restrict__ Abf, const short* __restrict__ Wbf,
              const float* __restrict__ bq, const float* __restrict__ bk,
              const float* __restrict__ bv, short* __restrict__ oq,
              short* __restrict__ ok_, short* __restrict__ ov)
{
  __shared__ short a_s[128][32];
  __shared__ short w_s[128][32];

  const int mode = blockIdx.z;
  const short* A = Abf + (size_t)mode * AN;
  const short* W = Wbf + (size_t)mode * EE;
  const float* bias = (mode == 0) ? bq : (mode == 1) ? bk : bv;

  const int m0 = blockIdx.y * 128;
  const int n0 = blockIdx.x * 128;
  const int t = threadIdx.x;
  const int lane = t & 63;
  const int wv = t >> 6;
  const int wr = wv >> 1;
  const int wc = wv & 1;
  const int lr = lane & 15;
  const int lg = lane >> 4;

  f32x4 acc[4][4];
  const f32x4 zero = {0.f, 0.f, 0.f, 0.f};
  #pragma unroll
  for (int i = 0; i < 4; ++i)
    #pragma unroll
    for (int j = 0; j < 4; ++j) acc[i][j] = zero;

  // staging: 8 gload16 instrs per 128x32 tile; wave wv issues instrs g0, g0+1
  const int g0 = wv * 2;
  const int srow = lane >> 2;
  const int scol = (lane & 3) * 8;
  const short* aptr0 = A + (size_t)(m0 + g0 * 16 + srow) * H_E + scol;
  const short* aptr1 = aptr0 + 16 * H_E;
  const short* wptr0 = W + (size_t)(n0 + g0 * 16 + srow) * H_E + scol;
  const short* wptr1 = wptr0 + 16 * H_E;
  short* adst0 = &a_s[0][0] + g0 * 512;
  short* adst1 = adst0 + 512;
  short* wdst0 = &w_s[0][0] + g0 * 512;
  short* wdst1 = wdst0 + 512;

  for (int kt = 0; kt < H_E / 32; ++kt) {
    const int ko = kt * 32;
    __syncthreads();
    gload16(aptr0 + ko, adst0);
    gload16(aptr1 + ko, adst1);
    gload16(wptr0 + ko, wdst0);
    gload16(wptr1 + ko, wdst1);
    __syncthreads();
    bf16x8 af[4], wf[4];
    #pragma unroll
    for (int i = 0; i < 4; ++i)
      af[i] = *reinterpret_cast<const bf16x8*>(&a_s[wr * 64 + i * 16 + lr][lg * 8]);
    #pragma unroll
    for (int j = 0; j < 4; ++j)
      wf[j] = *reinterpret_cast<const bf16x8*>(&w_s[wc * 64 + j * 16 + lr][lg * 8]);
    #pragma unroll
    for (int i = 0; i < 4; ++i)
      #pragma unroll
      for (int j = 0; j < 4; ++j)
        acc[i][j] = __builtin_amdgcn_mfma_f32_16x16x32_bf16(af[i], wf[j], acc[i][j], 0, 0, 0);
  }

  #pragma unroll
  for (int j = 0; j < 4; ++j) {
    const int gn = n0 + wc * 64 + j * 16 + lr;
    const float bvl = bias[gn];
    const int hh = gn >> 6, dd = gn & 63;
    #pragma unroll
    for (int i = 0; i < 4; ++i) {
      #pragma unroll
      for (int e = 0; e < 4; ++e) {
        const int gm = m0 + wr * 64 + i * 16 + lg * 4 + e;
        const float val = acc[i][j][e] + bvl;
        const int bb = gm >> 10, ll = gm & 1023;
        if (mode == 0)
          oq[((size_t)(bb * H_NH + hh) * H_L + ll) * H_HD + dd] = cvtbf(val * 0.125f);
        else if (mode == 1)
          ok_[((size_t)(bb * H_NH + hh) * H_S + ll) * H_HD + dd] = cvtbf(val);
        else
          ov[((size_t)(bb * H_NH + hh) * H_HD + dd) * H_S + ll] = cvtbf(val);
      }
    }
  }
}

// Output projection, same m97 structure; fp32 linear epilogue into d_out.
__global__ __launch_bounds__(256)
void out_gemm(const short* __restrict__ A, const short* __restrict__ W,
              const float* __restrict__ bias, float* __restrict__ outp)
{
  __shared__ short a_s[128][32];
  __shared__ short w_s[128][32];

  const int m0 = blockIdx.y * 128;
  const int n0 = blockIdx.x * 128;
  const int t = threadIdx.x;
  const int lane = t & 63;
  const int wv = t >> 6;
  const int wr = wv >> 1;
  const int wc = wv & 1;
  const int lr = lane & 15;
  const int lg = lane >> 4;

  f32x4 acc[4][4];
  const f32x4 zero = {0.f, 0.f, 0.f, 0.f};
  #pragma unroll
  for (int i = 0; i < 4; ++i)
    #pragma unroll
    for (int j = 0; j < 4; ++j) acc[i][j] = zero;

  const int g0 = wv * 2;
  const int srow = lane >> 2;
  const int scol = (lane & 3) * 8;
  const short* aptr0 = A + (size_t)(m0 + g0 * 16 + srow) * H_E + scol;
  const short* aptr1 = aptr0 + 16 * H_E;
  const short* wptr0 = W + (size_t)(n0 + g0 * 16 + srow) * H_E + scol;
  const short* wptr1 = wptr0 + 16 * H_E;
  short* adst0 = &a_s[0][0] + g0 * 512;
  short* adst1 = adst0 + 512;
  short* wdst0 = &w_s[0][0] + g0 * 512;
  short* wdst1 = wdst0 + 512;

  for (int kt = 0; kt < H_E / 32; ++kt) {
    const int ko = kt * 32;
    __syncthreads();
    gload16(aptr0 + ko, adst0);
    gload16(aptr1 + ko, adst1);
    gload16(wptr0 + ko, wdst0);
    gload16(wptr1 + ko, wdst1);
    __syncthreads();
    bf16x8 af[4], wf[4];
    #pragma unroll
    for (int i = 0; i < 4; ++i)
      af[i] = *reinterpret_cast<const bf16x8*>(&a_s[wr * 64 + i * 16 + lr][lg * 8]);
    #pragma unroll
    for (int j = 0; j < 4; ++j)
      wf[j] = *reinterpret_cast<const bf16x8*>(&w_s[wc * 64 + j * 16 + lr][lg * 8]);
    #pragma unroll
    for (int i = 0; i < 4; ++i)
      #pragma unroll
      for (int j = 0; j < 4; ++j)
        acc[i][j] = __builtin_amdgcn_mfma_f32_16x16x32_bf16(af[i], wf[j], acc[i][j], 0, 0, 0);
  }

  #pragma unroll
  for (int j = 0; j < 4; ++j) {
    const int gn = n0 + wc * 64 + j * 16 + lr;
    const float bvl = bias[gn];
    #pragma unroll
    for (int i = 0; i < 4; ++i) {
      #pragma unroll
      for (int e = 0; e < 4; ++e) {
        const int gm = m0 + wr * 64 + i * 16 + lg * 4 + e;
        outp[(size_t)gm * H_E + gn] = acc[i][j][e] + bvl;
      }
    }
  }
}

// Flash attention: block = (b, h, 64-row q tile); 4 waves x 16 q-rows. (unchanged)
__global__ __launch_bounds__(256)
void smha_attn(const short* __restrict__ q, const short* __restrict__ k,
               const short* __restrict__ vt, const float* __restrict__ kpm,
               const float* __restrict__ sf, short* __restrict__ outp)
{
  __shared__ short k_s[64][72];
  __shared__ short v_s[64][72];
  __shared__ short p_s[4][16][72];

  const int blk = blockIdx.x;
  const int qt = blk & 15;
  const int hh = (blk >> 4) % H_NH;
  const int bb = blk / (16 * H_NH);
  const int bh = bb * H_NH + hh;
  const int t = threadIdx.x;
  const int wv = t >> 6;
  const int lane = t & 63;
  const int lr = lane & 15;
  const int lg = lane >> 4;

  const int q0 = qt * 64 + wv * 16;

  bf16x8 qf[2];
  #pragma unroll
  for (int kk = 0; kk < 2; ++kk)
    qf[kk] = *reinterpret_cast<const bf16x8*>(
        &q[((size_t)bh * H_L + q0 + lr) * H_HD + kk * 32 + lg * 8]);

  const float sfh = sf[hh];

  f32x4 o_acc[4];
  const f32x4 zero = {0.f, 0.f, 0.f, 0.f};
  #pragma unroll
  for (int di = 0; di < 4; ++di) o_acc[di] = zero;
  float mrow[4], lrow[4];
  #pragma unroll
  for (int j = 0; j < 4; ++j) { mrow[j] = -1e30f; lrow[j] = 0.f; }

  const int srow = t >> 2;
  const int scol = (t & 3) * 16;

  const short* kp = &k[((size_t)bh * H_S + srow) * H_HD + scol];
  const short* vp = &vt[((size_t)bh * H_HD + srow) * H_S + scol];
  bf16x8 kr0 = *reinterpret_cast<const bf16x8*>(kp);
  bf16x8 kr1 = *reinterpret_cast<const bf16x8*>(kp + 8);
  bf16x8 vr0 = *reinterpret_cast<const bf16x8*>(vp);
  bf16x8 vr1 = *reinterpret_cast<const bf16x8*>(vp + 8);

  for (int kv = 0; kv < H_S / 64; ++kv) {
    const int s0 = kv * 64;
    __syncthreads();
    *reinterpret_cast<bf16x8*>(&k_s[srow][scol])     = kr0;
    *reinterpret_cast<bf16x8*>(&k_s[srow][scol + 8]) = kr1;
    *reinterpret_cast<bf16x8*>(&v_s[srow][scol])     = vr0;
    *reinterpret_cast<bf16x8*>(&v_s[srow][scol + 8]) = vr1;
    __syncthreads();
    if (kv + 1 < H_S / 64) {
      const short* kpn = kp + (size_t)(kv + 1) * 64 * H_HD;
      const short* vpn = vp + (size_t)(kv + 1) * 64;
      kr0 = *reinterpret_cast<const bf16x8*>(kpn);
      kr1 = *reinterpret_cast<const bf16x8*>(kpn + 8);
      vr0 = *reinterpret_cast<const bf16x8*>(vpn);
      vr1 = *reinterpret_cast<const bf16x8*>(vpn + 8);
    }

    float bias_c[4];
    #pragma unroll
    for (int ni = 0; ni < 4; ++ni)
      bias_c[ni] = kpm[bb * H_S + s0 + ni * 16 + lr] * sfh;

    f32x4 sc[4];
    #pragma unroll
    for (int ni = 0; ni < 4; ++ni) sc[ni] = zero;
    #pragma unroll
    for (int kk = 0; kk < 2; ++kk) {
      #pragma unroll
      for (int ni = 0; ni < 4; ++ni) {
        const bf16x8 bfr = *reinterpret_cast<const bf16x8*>(&k_s[ni * 16 + lr][kk * 32 + lg * 8]);
        sc[ni] = __builtin_amdgcn_mfma_f32_16x16x32_bf16(qf[kk], bfr, sc[ni], 0, 0, 0);
      }
    }

    #pragma unroll
    for (int j = 0; j < 4; ++j) {
      float mx = -1e30f;
      #pragma unroll
      for (int ni = 0; ni < 4; ++ni) {
        sc[ni][j] += bias_c[ni];
        mx = fmaxf(mx, sc[ni][j]);
      }
      mx = fmaxf(mx, __shfl_xor(mx, 1));
      mx = fmaxf(mx, __shfl_xor(mx, 2));
      mx = fmaxf(mx, __shfl_xor(mx, 4));
      mx = fmaxf(mx, __shfl_xor(mx, 8));
      if (!__all(mx <= mrow[j] + 8.0f)) {
        const float mnew = fmaxf(mrow[j], mx);
        const float scal = __expf(mrow[j] - mnew);
        lrow[j] *= scal;
        #pragma unroll
        for (int di = 0; di < 4; ++di) o_acc[di][j] *= scal;
        mrow[j] = mnew;
      }
      float rsum = 0.f;
      #pragma unroll
      for (int ni = 0; ni < 4; ++ni) {
        const float p = __expf(sc[ni][j] - mrow[j]);
        sc[ni][j] = p;
        rsum += p;
      }
      rsum += __shfl_xor(rsum, 1);
      rsum += __shfl_xor(rsum, 2);
      rsum += __shfl_xor(rsum, 4);
      rsum += __shfl_xor(rsum, 8);
      lrow[j] += rsum;
    }

    #pragma unroll
    for (int ni = 0; ni < 4; ++ni)
      #pragma unroll
      for (int j = 0; j < 4; ++j)
        p_s[wv][lg * 4 + j][ni * 16 + lr] = cvtbf(sc[ni][j]);

    #pragma unroll
    for (int kk = 0; kk < 2; ++kk) {
      const bf16x8 pf = *reinterpret_cast<const bf16x8*>(&p_s[wv][lr][kk * 32 + lg * 8]);
      #pragma unroll
      for (int di = 0; di < 4; ++di) {
        const bf16x8 vfr = *reinterpret_cast<const bf16x8*>(&v_s[di * 16 + lr][kk * 32 + lg * 8]);
        o_acc[di] = __builtin_amdgcn_mfma_f32_16x16x32_bf16(pf, vfr, o_acc[di], 0, 0, 0);
      }
    }
  }

  #pragma unroll
  for (int j = 0; j < 4; ++j) {
    const float rl = 1.0f / lrow[j];
    const int gq = q0 + lg * 4 + j;
    #pragma unroll
    for (int di = 0; di < 4; ++di)
      outp[((size_t)bb * H_L + gq) * H_E + hh * H_HD + di * 16 + lr] =
          cvtbf(o_acc[di][j] * rl);
  }
}

extern "C" void kernel_launch(void* const* d_in, const int* in_sizes, int n_in,
                              void* d_out, int out_size, void* d_ws, size_t ws_size,
                              hipStream_t stream)
{
  // 0 query, 1 key, 2 value, 3 kpm, 4 Wq, 5 bq, 6 Wk, 7 bk, 8 Wv, 9 bv,
  // 10 Wo, 11 bo, 12 scaling_factors
  short* ws_w  = (short*)d_ws;                    // 4*EE bf16 weights
  short* ws_a  = ws_w + (size_t)4 * EE;           // 3*AN bf16 activations
  short* ws_q  = ws_a + (size_t)3 * AN;
  short* ws_k  = ws_q + AN;
  short* ws_vt = ws_k + AN;
  short* ws_at = ws_a;                            // alias: ws_a dead after qkv_gemm

  conv_bf16<<<dim3(AN / 2048, 7), 256, 0, stream>>>(
      (const float*)d_in[4], (const float*)d_in[6], (const float*)d_in[8],
      (const float*)d_in[10], (const float*)d_in[0], (const float*)d_in[1],
      (const float*)d_in[2], ws_w, ws_a);

  qkv_gemm<<<dim3(H_E / 128, (H_BS * H_L) / 128, 3), 256, 0, stream>>>(
      ws_a, ws_w, (const float*)d_in[5], (const float*)d_in[7],
      (const float*)d_in[9], ws_q, ws_k, ws_vt);

  smha_attn<<<H_BS * H_NH * (H_L / 64), 256, 0, stream>>>(
      ws_q, ws_k, ws_vt, (const float*)d_in[3], (const float*)d_in[12], ws_at);

  out_gemm<<<dim3(H_E / 128, (H_BS * H_L) / 128), 256, 0, stream>>>(
      ws_at, ws_w + (size_t)3 * EE, (const float*)d_in[11], (float*)d_out);
}

// Round 4
// 289.956 us; speedup vs baseline: 1.2630x; 1.1012x over previous
//
#include <hip/hip_runtime.h>
#include <hip/hip_bf16.h>

typedef __attribute__((ext_vector_type(8))) short bf16x8;
typedef __attribute__((ext_vector_type(4))) short bf16x4;
typedef __attribute__((ext_vector_type(4))) float f32x4;

#define H_BS 8
#define H_L 1024
#define H_S 1024
#define H_E 768
#define H_NH 12
#define H_HD 64
#define EE (H_E * H_E)                 // 589824
#define AN (H_BS * H_L * H_E)          // 6291456
#define LOG2E 1.44269504f

static __device__ __forceinline__ short cvtbf(float f) {
  __hip_bfloat16 h = __float2bfloat16(f);
  return *reinterpret_cast<short*>(&h);
}

static __device__ __forceinline__ float fexp2(float x) {
#if __has_builtin(__builtin_amdgcn_exp2f)
  return __builtin_amdgcn_exp2f(x);
#else
  return __expf(x * 0.69314718056f);
#endif
}

static __device__ __forceinline__ void gload16(const void* g, void* l) {
  __builtin_amdgcn_global_load_lds(
      (const __attribute__((address_space(1))) void*)g,
      (__attribute__((address_space(3))) void*)l, 16, 0, 0);
}

// fp32 -> bf16 for 4 weight matrices + 3 activation tensors.
__global__ __launch_bounds__(256)
void conv_bf16(const float* __restrict__ w0, const float* __restrict__ w1,
               const float* __restrict__ w2, const float* __restrict__ w3,
               const float* __restrict__ a0, const float* __restrict__ a1,
               const float* __restrict__ a2,
               short* __restrict__ ws_w, short* __restrict__ ws_a)
{
  const int y = blockIdx.y;
  const float* src;
  short* dst;
  int n;
  if (y < 4) {
    src = (y == 0) ? w0 : (y == 1) ? w1 : (y == 2) ? w2 : w3;
    dst = ws_w + (size_t)y * EE;
    n = EE;
  } else {
    src = (y == 4) ? a0 : (y == 5) ? a1 : a2;
    dst = ws_a + (size_t)(y - 4) * AN;
    n = AN;
  }
  const int i = (blockIdx.x * 256 + threadIdx.x) * 8;
  if (i >= n) return;
  const float4 f0 = *reinterpret_cast<const float4*>(src + i);
  const float4 f1 = *reinterpret_cast<const float4*>(src + i + 4);
  bf16x8 r;
  r[0] = cvtbf(f0.x); r[1] = cvtbf(f0.y); r[2] = cvtbf(f0.z); r[3] = cvtbf(f0.w);
  r[4] = cvtbf(f1.x); r[5] = cvtbf(f1.y); r[6] = cvtbf(f1.z); r[7] = cvtbf(f1.w);
  *reinterpret_cast<bf16x8*>(dst + i) = r;
}

// m97-structure GEMM: C[M,N] = A[M,768] @ W[N,768]^T + b, tile 128x128x32.
// blockIdx.z = mode (0 q [*log2e/8], 1 k, 2 v^T), scatter epilogue.
__global__ __launch_bounds__(256)
void qkv_gemm(const short* __restrict__ Abf, const short* __restrict__ Wbf,
              const float* __restrict__ bq, const float* __restrict__ bk,
              const float* __restrict__ bv, short* __restrict__ oq,
              short* __restrict__ ok_, short* __restrict__ ov)
{
  __shared__ short a_s[128][32];
  __shared__ short w_s[128][32];

  const int mode = blockIdx.z;
  const short* A = Abf + (size_t)mode * AN;
  const short* W = Wbf + (size_t)mode * EE;
  const float* bias = (mode == 0) ? bq : (mode == 1) ? bk : bv;

  const int m0 = blockIdx.y * 128;
  const int n0 = blockIdx.x * 128;
  const int t = threadIdx.x;
  const int lane = t & 63;
  const int wv = t >> 6;
  const int wr = wv >> 1;
  const int wc = wv & 1;
  const int lr = lane & 15;
  const int lg = lane >> 4;

  f32x4 acc[4][4];
  const f32x4 zero = {0.f, 0.f, 0.f, 0.f};
  #pragma unroll
  for (int i = 0; i < 4; ++i)
    #pragma unroll
    for (int j = 0; j < 4; ++j) acc[i][j] = zero;

  const int g0 = wv * 2;
  const int srow = lane >> 2;
  const int scol = (lane & 3) * 8;
  const short* aptr0 = A + (size_t)(m0 + g0 * 16 + srow) * H_E + scol;
  const short* aptr1 = aptr0 + 16 * H_E;
  const short* wptr0 = W + (size_t)(n0 + g0 * 16 + srow) * H_E + scol;
  const short* wptr1 = wptr0 + 16 * H_E;
  short* adst0 = &a_s[0][0] + g0 * 512;
  short* adst1 = adst0 + 512;
  short* wdst0 = &w_s[0][0] + g0 * 512;
  short* wdst1 = wdst0 + 512;

  for (int kt = 0; kt < H_E / 32; ++kt) {
    const int ko = kt * 32;
    __syncthreads();
    gload16(aptr0 + ko, adst0);
    gload16(aptr1 + ko, adst1);
    gload16(wptr0 + ko, wdst0);
    gload16(wptr1 + ko, wdst1);
    __syncthreads();
    bf16x8 af[4], wf[4];
    #pragma unroll
    for (int i = 0; i < 4; ++i)
      af[i] = *reinterpret_cast<const bf16x8*>(&a_s[wr * 64 + i * 16 + lr][lg * 8]);
    #pragma unroll
    for (int j = 0; j < 4; ++j)
      wf[j] = *reinterpret_cast<const bf16x8*>(&w_s[wc * 64 + j * 16 + lr][lg * 8]);
    #pragma unroll
    for (int i = 0; i < 4; ++i)
      #pragma unroll
      for (int j = 0; j < 4; ++j)
        acc[i][j] = __builtin_amdgcn_mfma_f32_16x16x32_bf16(af[i], wf[j], acc[i][j], 0, 0, 0);
  }

  #pragma unroll
  for (int j = 0; j < 4; ++j) {
    const int gn = n0 + wc * 64 + j * 16 + lr;
    const float bvl = bias[gn];
    const int hh = gn >> 6, dd = gn & 63;
    #pragma unroll
    for (int i = 0; i < 4; ++i) {
      #pragma unroll
      for (int e = 0; e < 4; ++e) {
        const int gm = m0 + wr * 64 + i * 16 + lg * 4 + e;
        const float val = acc[i][j][e] + bvl;
        const int bb = gm >> 10, ll = gm & 1023;
        if (mode == 0)   // fold 1/sqrt(64) * log2e into Q
          oq[((size_t)(bb * H_NH + hh) * H_L + ll) * H_HD + dd] = cvtbf(val * (0.125f * LOG2E));
        else if (mode == 1)
          ok_[((size_t)(bb * H_NH + hh) * H_S + ll) * H_HD + dd] = cvtbf(val);
        else
          ov[((size_t)(bb * H_NH + hh) * H_HD + dd) * H_S + ll] = cvtbf(val);
      }
    }
  }
}

// Output projection, m97 structure; fp32 linear epilogue into d_out.
__global__ __launch_bounds__(256)
void out_gemm(const short* __restrict__ A, const short* __restrict__ W,
              const float* __restrict__ bias, float* __restrict__ outp)
{
  __shared__ short a_s[128][32];
  __shared__ short w_s[128][32];

  const int m0 = blockIdx.y * 128;
  const int n0 = blockIdx.x * 128;
  const int t = threadIdx.x;
  const int lane = t & 63;
  const int wv = t >> 6;
  const int wr = wv >> 1;
  const int wc = wv & 1;
  const int lr = lane & 15;
  const int lg = lane >> 4;

  f32x4 acc[4][4];
  const f32x4 zero = {0.f, 0.f, 0.f, 0.f};
  #pragma unroll
  for (int i = 0; i < 4; ++i)
    #pragma unroll
    for (int j = 0; j < 4; ++j) acc[i][j] = zero;

  const int g0 = wv * 2;
  const int srow = lane >> 2;
  const int scol = (lane & 3) * 8;
  const short* aptr0 = A + (size_t)(m0 + g0 * 16 + srow) * H_E + scol;
  const short* aptr1 = aptr0 + 16 * H_E;
  const short* wptr0 = W + (size_t)(n0 + g0 * 16 + srow) * H_E + scol;
  const short* wptr1 = wptr0 + 16 * H_E;
  short* adst0 = &a_s[0][0] + g0 * 512;
  short* adst1 = adst0 + 512;
  short* wdst0 = &w_s[0][0] + g0 * 512;
  short* wdst1 = wdst0 + 512;

  for (int kt = 0; kt < H_E / 32; ++kt) {
    const int ko = kt * 32;
    __syncthreads();
    gload16(aptr0 + ko, adst0);
    gload16(aptr1 + ko, adst1);
    gload16(wptr0 + ko, wdst0);
    gload16(wptr1 + ko, wdst1);
    __syncthreads();
    bf16x8 af[4], wf[4];
    #pragma unroll
    for (int i = 0; i < 4; ++i)
      af[i] = *reinterpret_cast<const bf16x8*>(&a_s[wr * 64 + i * 16 + lr][lg * 8]);
    #pragma unroll
    for (int j = 0; j < 4; ++j)
      wf[j] = *reinterpret_cast<const bf16x8*>(&w_s[wc * 64 + j * 16 + lr][lg * 8]);
    #pragma unroll
    for (int i = 0; i < 4; ++i)
      #pragma unroll
      for (int j = 0; j < 4; ++j)
        acc[i][j] = __builtin_amdgcn_mfma_f32_16x16x32_bf16(af[i], wf[j], acc[i][j], 0, 0, 0);
  }

  #pragma unroll
  for (int j = 0; j < 4; ++j) {
    const int gn = n0 + wc * 64 + j * 16 + lr;
    const float bvl = bias[gn];
    #pragma unroll
    for (int i = 0; i < 4; ++i) {
      #pragma unroll
      for (int e = 0; e < 4; ++e) {
        const int gm = m0 + wr * 64 + i * 16 + lg * 4 + e;
        outp[(size_t)gm * H_E + gn] = acc[i][j][e] + bvl;
      }
    }
  }
}

// Flash attention, SWAPPED QK^T: sc = mfma(K_frag, Q_frag) -> col=q=lane&15,
// rows=s. Softmax rows are lane-local (q=lr per lane); bias enters as the
// MFMA C-initializer; exp in log2 domain (Q pre-scaled by log2e/8).
__global__ __launch_bounds__(256)
void smha_attn(const short* __restrict__ q, const short* __restrict__ k,
               const short* __restrict__ vt, const float* __restrict__ kpm,
               const float* __restrict__ sf, short* __restrict__ outp)
{
  __shared__ short k_s[64][72];
  __shared__ short v_s[64][72];
  __shared__ short p_s[4][16][72];   // per-wave P [q][s]

  const int blk = blockIdx.x;
  const int qt = blk & 15;
  const int hh = (blk >> 4) % H_NH;
  const int bb = blk / (16 * H_NH);
  const int bh = bb * H_NH + hh;
  const int t = threadIdx.x;
  const int wv = t >> 6;
  const int lane = t & 63;
  const int lr = lane & 15;
  const int lg = lane >> 4;

  const int q0 = qt * 64 + wv * 16;

  bf16x8 qf[2];
  #pragma unroll
  for (int kk = 0; kk < 2; ++kk)
    qf[kk] = *reinterpret_cast<const bf16x8*>(
        &q[((size_t)bh * H_L + q0 + lr) * H_HD + kk * 32 + lg * 8]);

  const float sfh = sf[hh] * LOG2E;
  const float* kpmb = kpm + bb * H_S;

  f32x4 o_acc[4];
  const f32x4 zero = {0.f, 0.f, 0.f, 0.f};
  #pragma unroll
  for (int di = 0; di < 4; ++di) o_acc[di] = zero;
  float mrow = -1e30f, lrow = 0.f;   // per-lane state for q-row lr

  const int srow = t >> 2;
  const int scol = (t & 3) * 16;

  const short* kp = &k[((size_t)bh * H_S + srow) * H_HD + scol];
  const short* vp = &vt[((size_t)bh * H_HD + srow) * H_S + scol];
  bf16x8 kr0 = *reinterpret_cast<const bf16x8*>(kp);
  bf16x8 kr1 = *reinterpret_cast<const bf16x8*>(kp + 8);
  bf16x8 vr0 = *reinterpret_cast<const bf16x8*>(vp);
  bf16x8 vr1 = *reinterpret_cast<const bf16x8*>(vp + 8);

  for (int kv = 0; kv < H_S / 64; ++kv) {
    const int s0 = kv * 64;
    __syncthreads();
    *reinterpret_cast<bf16x8*>(&k_s[srow][scol])     = kr0;
    *reinterpret_cast<bf16x8*>(&k_s[srow][scol + 8]) = kr1;
    *reinterpret_cast<bf16x8*>(&v_s[srow][scol])     = vr0;
    *reinterpret_cast<bf16x8*>(&v_s[srow][scol + 8]) = vr1;
    __syncthreads();
    if (kv + 1 < H_S / 64) {
      const short* kpn = kp + (size_t)(kv + 1) * 64 * H_HD;
      const short* vpn = vp + (size_t)(kv + 1) * 64;
      kr0 = *reinterpret_cast<const bf16x8*>(kpn);
      kr1 = *reinterpret_cast<const bf16x8*>(kpn + 8);
      vr0 = *reinterpret_cast<const bf16x8*>(vpn);
      vr1 = *reinterpret_cast<const bf16x8*>(vpn + 8);
    }

    // S^T = K Q^T + bias: C-init with bias (rows = s -> per-reg values)
    f32x4 sc[4];
    #pragma unroll
    for (int ni = 0; ni < 4; ++ni) {
      const f32x4 kp4 = *reinterpret_cast<const f32x4*>(&kpmb[s0 + ni * 16 + lg * 4]);
      #pragma unroll
      for (int e = 0; e < 4; ++e) sc[ni][e] = kp4[e] * sfh;
    }
    #pragma unroll
    for (int kk = 0; kk < 2; ++kk) {
      #pragma unroll
      for (int ni = 0; ni < 4; ++ni) {
        const bf16x8 kf = *reinterpret_cast<const bf16x8*>(&k_s[ni * 16 + lr][kk * 32 + lg * 8]);
        sc[ni] = __builtin_amdgcn_mfma_f32_16x16x32_bf16(kf, qf[kk], sc[ni], 0, 0, 0);
      }
    }

    // in-lane row max (16 s-values of row q=lr), then 2 shuffles
    float pm[4];
    #pragma unroll
    for (int ni = 0; ni < 4; ++ni)
      pm[ni] = fmaxf(fmaxf(sc[ni][0], sc[ni][1]), fmaxf(sc[ni][2], sc[ni][3]));
    float mx = fmaxf(fmaxf(pm[0], pm[1]), fmaxf(pm[2], pm[3]));
    mx = fmaxf(mx, __shfl_xor(mx, 16));
    mx = fmaxf(mx, __shfl_xor(mx, 32));

    // defer-max: one wave-uniform branch per tile (threshold in log2 units)
    if (!__all(mx <= mrow + 11.5f)) {
      const float mnew = fmaxf(mrow, mx);
      const float scal = fexp2(mrow - mnew);
      lrow *= scal;
      float sj[4];
      #pragma unroll
      for (int j = 0; j < 4; ++j) sj[j] = __shfl(scal, lg * 4 + j);
      #pragma unroll
      for (int di = 0; di < 4; ++di)
        #pragma unroll
        for (int j = 0; j < 4; ++j) o_acc[di][j] *= sj[j];
      mrow = mnew;
    }

    // P = 2^(S - m), in-lane sum + 2 shuffles
    float ps[4];
    #pragma unroll
    for (int ni = 0; ni < 4; ++ni) {
      #pragma unroll
      for (int e = 0; e < 4; ++e) sc[ni][e] = fexp2(sc[ni][e] - mrow);
      ps[ni] = (sc[ni][0] + sc[ni][1]) + (sc[ni][2] + sc[ni][3]);
    }
    float rs = (ps[0] + ps[1]) + (ps[2] + ps[3]);
    rs += __shfl_xor(rs, 16);
    rs += __shfl_xor(rs, 32);
    lrow += rs;

    // packed P write: lane owns row q=lr, s-segment ni*16+lg*4..+3
    #pragma unroll
    for (int ni = 0; ni < 4; ++ni) {
      bf16x4 pk4;
      pk4[0] = cvtbf(sc[ni][0]); pk4[1] = cvtbf(sc[ni][1]);
      pk4[2] = cvtbf(sc[ni][2]); pk4[3] = cvtbf(sc[ni][3]);
      *reinterpret_cast<bf16x4*>(&p_s[wv][lr][ni * 16 + lg * 4]) = pk4;
    }

    // O += P V (unchanged)
    #pragma unroll
    for (int kk = 0; kk < 2; ++kk) {
      const bf16x8 pf = *reinterpret_cast<const bf16x8*>(&p_s[wv][lr][kk * 32 + lg * 8]);
      #pragma unroll
      for (int di = 0; di < 4; ++di) {
        const bf16x8 vfr = *reinterpret_cast<const bf16x8*>(&v_s[di * 16 + lr][kk * 32 + lg * 8]);
        o_acc[di] = __builtin_amdgcn_mfma_f32_16x16x32_bf16(pf, vfr, o_acc[di], 0, 0, 0);
      }
    }
  }

  // epilogue: O rows are q = lg*4+j; fetch l from lane (lg*4+j)
  #pragma unroll
  for (int j = 0; j < 4; ++j) {
    const float rl = 1.0f / __shfl(lrow, lg * 4 + j);
    const int gq = q0 + lg * 4 + j;
    #pragma unroll
    for (int di = 0; di < 4; ++di)
      outp[((size_t)bb * H_L + gq) * H_E + hh * H_HD + di * 16 + lr] =
          cvtbf(o_acc[di][j] * rl);
  }
}

extern "C" void kernel_launch(void* const* d_in, const int* in_sizes, int n_in,
                              void* d_out, int out_size, void* d_ws, size_t ws_size,
                              hipStream_t stream)
{
  // 0 query, 1 key, 2 value, 3 kpm, 4 Wq, 5 bq, 6 Wk, 7 bk, 8 Wv, 9 bv,
  // 10 Wo, 11 bo, 12 scaling_factors
  short* ws_w  = (short*)d_ws;                    // 4*EE bf16 weights
  short* ws_a  = ws_w + (size_t)4 * EE;           // 3*AN bf16 activations
  short* ws_q  = ws_a + (size_t)3 * AN;
  short* ws_k  = ws_q + AN;
  short* ws_vt = ws_k + AN;
  short* ws_at = ws_a;                            // alias: ws_a dead after qkv_gemm

  conv_bf16<<<dim3(AN / 2048, 7), 256, 0, stream>>>(
      (const float*)d_in[4], (const float*)d_in[6], (const float*)d_in[8],
      (const float*)d_in[10], (const float*)d_in[0], (const float*)d_in[1],
      (const float*)d_in[2], ws_w, ws_a);

  qkv_gemm<<<dim3(H_E / 128, (H_BS * H_L) / 128, 3), 256, 0, stream>>>(
      ws_a, ws_w, (const float*)d_in[5], (const float*)d_in[7],
      (const float*)d_in[9], ws_q, ws_k, ws_vt);

  smha_attn<<<H_BS * H_NH * (H_L / 64), 256, 0, stream>>>(
      ws_q, ws_k, ws_vt, (const float*)d_in[3], (const float*)d_in[12], ws_at);

  out_gemm<<<dim3(H_E / 128, (H_BS * H_L) / 128), 256, 0, stream>>>(
      ws_at, ws_w + (size_t)3 * EE, (const float*)d_in[11], (float*)d_out);
}

// Round 7
// 271.736 us; speedup vs baseline: 1.3476x; 1.0671x over previous
//
#include <hip/hip_runtime.h>
#include <hip/hip_bf16.h>

typedef __attribute__((ext_vector_type(8))) short bf16x8;
typedef __attribute__((ext_vector_type(4))) short bf16x4;
typedef __attribute__((ext_vector_type(4))) float f32x4;

#define H_BS 8
#define H_L 1024
#define H_S 1024
#define H_E 768
#define H_NH 12
#define H_HD 64
#define EE (H_E * H_E)                 // 589824
#define AN (H_BS * H_L * H_E)          // 6291456
#define LOG2E 1.44269504f
#define NKT (H_E / 32)                 // 24 k-steps

static __device__ __forceinline__ short cvtbf(float f) {
  __hip_bfloat16 h = __float2bfloat16(f);
  return *reinterpret_cast<short*>(&h);
}

static __device__ __forceinline__ float fexp2(float x) {
#if __has_builtin(__builtin_amdgcn_exp2f)
  return __builtin_amdgcn_exp2f(x);
#else
  return __expf(x * 0.69314718056f);
#endif
}

static __device__ __forceinline__ void gload16(const void* g, void* l) {
  __builtin_amdgcn_global_load_lds(
      (const __attribute__((address_space(1))) void*)g,
      (__attribute__((address_space(3))) void*)l, 16, 0, 0);
}

// fp32 -> bf16 for 4 weight matrices + 3 activation tensors.
__global__ __launch_bounds__(256)
void conv_bf16(const float* __restrict__ w0, const float* __restrict__ w1,
               const float* __restrict__ w2, const float* __restrict__ w3,
               const float* __restrict__ a0, const float* __restrict__ a1,
               const float* __restrict__ a2,
               short* __restrict__ ws_w, short* __restrict__ ws_a)
{
  const int y = blockIdx.y;
  const float* src;
  short* dst;
  int n;
  if (y < 4) {
    src = (y == 0) ? w0 : (y == 1) ? w1 : (y == 2) ? w2 : w3;
    dst = ws_w + (size_t)y * EE;
    n = EE;
  } else {
    src = (y == 4) ? a0 : (y == 5) ? a1 : a2;
    dst = ws_a + (size_t)(y - 4) * AN;
    n = AN;
  }
  const int i = (blockIdx.x * 256 + threadIdx.x) * 8;
  if (i >= n) return;
  const float4 f0 = *reinterpret_cast<const float4*>(src + i);
  const float4 f1 = *reinterpret_cast<const float4*>(src + i + 4);
  bf16x8 r;
  r[0] = cvtbf(f0.x); r[1] = cvtbf(f0.y); r[2] = cvtbf(f0.z); r[3] = cvtbf(f0.w);
  r[4] = cvtbf(f1.x); r[5] = cvtbf(f1.y); r[6] = cvtbf(f1.z); r[7] = cvtbf(f1.w);
  *reinterpret_cast<bf16x8*>(dst + i) = r;
}

// 128x128x32 GEMM, 2-phase double-buffered global_load_lds staging (T3-min).
// blockIdx.z = mode (0 q [*log2e/8], 1 k, 2 v^T via LDS-transpose epilogue).
__global__ __launch_bounds__(256)
void qkv_gemm(const short* __restrict__ Abf, const short* __restrict__ Wbf,
              const float* __restrict__ bq, const float* __restrict__ bk,
              const float* __restrict__ bv, short* __restrict__ oq,
              short* __restrict__ ok_, short* __restrict__ ov)
{
  // staging: buf b at smem + b*8192 (A 4096 shorts, then W 4096 shorts)
  // epilogue mode 2: reused as 128x132 transpose buffer
  __shared__ short smem[16896];

  const int mode = blockIdx.z;
  const short* A = Abf + (size_t)mode * AN;
  const short* W = Wbf + (size_t)mode * EE;
  const float* bias = (mode == 0) ? bq : (mode == 1) ? bk : bv;

  const int m0 = blockIdx.y * 128;
  const int n0 = blockIdx.x * 128;
  const int t = threadIdx.x;
  const int lane = t & 63;
  const int wv = t >> 6;
  const int wr = wv >> 1;
  const int wc = wv & 1;
  const int lr = lane & 15;
  const int lg = lane >> 4;

  f32x4 acc[4][4];
  const f32x4 zero = {0.f, 0.f, 0.f, 0.f};
  #pragma unroll
  for (int i = 0; i < 4; ++i)
    #pragma unroll
    for (int j = 0; j < 4; ++j) acc[i][j] = zero;

  const int g0 = wv * 2;
  const int srow = lane >> 2;
  const int scol = (lane & 3) * 8;
  const short* aptr0 = A + (size_t)(m0 + g0 * 16 + srow) * H_E + scol;
  const short* aptr1 = aptr0 + 16 * H_E;
  const short* wptr0 = W + (size_t)(n0 + g0 * 16 + srow) * H_E + scol;
  const short* wptr1 = wptr0 + 16 * H_E;

  // prologue: stage tile 0 into buf 0
  {
    short* b = smem;
    gload16(aptr0, b + g0 * 512);
    gload16(aptr1, b + g0 * 512 + 512);
    gload16(wptr0, b + 4096 + g0 * 512);
    gload16(wptr1, b + 4096 + g0 * 512 + 512);
  }
  __syncthreads();

  int cur = 0;
  for (int kt = 0; kt < NKT; ++kt) {
    if (kt + 1 < NKT) {              // issue next tile's loads (overlap w/ MFMA)
      const int ko = (kt + 1) * 32;
      short* b = smem + (cur ^ 1) * 8192;
      gload16(aptr0 + ko, b + g0 * 512);
      gload16(aptr1 + ko, b + g0 * 512 + 512);
      gload16(wptr0 + ko, b + 4096 + g0 * 512);
      gload16(wptr1 + ko, b + 4096 + g0 * 512 + 512);
    }
    const short* ab = smem + cur * 8192;
    const short* wb = ab + 4096;
    bf16x8 af[4], wf[4];
    #pragma unroll
    for (int i = 0; i < 4; ++i)
      af[i] = *reinterpret_cast<const bf16x8*>(&ab[(wr * 64 + i * 16 + lr) * 32 + lg * 8]);
    #pragma unroll
    for (int j = 0; j < 4; ++j)
      wf[j] = *reinterpret_cast<const bf16x8*>(&wb[(wc * 64 + j * 16 + lr) * 32 + lg * 8]);
    #pragma unroll
    for (int i = 0; i < 4; ++i)
      #pragma unroll
      for (int j = 0; j < 4; ++j)
        acc[i][j] = __builtin_amdgcn_mfma_f32_16x16x32_bf16(af[i], wf[j], acc[i][j], 0, 0, 0);
    __syncthreads();                 // drains this iter's prefetch + lgkm, 1 barrier/step
    cur ^= 1;
  }

  if (mode == 2) {
    // transpose epilogue: acc -> LDS [gn_local][gm_local] (row stride 132)
    #pragma unroll
    for (int j = 0; j < 4; ++j) {
      const int gnl = wc * 64 + j * 16 + lr;
      const float bvl = bias[n0 + gnl];
      #pragma unroll
      for (int i = 0; i < 4; ++i) {
        bf16x4 pk;
        #pragma unroll
        for (int e = 0; e < 4; ++e) pk[e] = cvtbf(acc[i][j][e] + bvl);
        *reinterpret_cast<bf16x4*>(&smem[gnl * 132 + wr * 64 + i * 16 + lg * 4]) = pk;
      }
    }
    __syncthreads();
    // coalesced store: per u, 16-lane groups write 256B contiguous
    const int bb = m0 >> 10;
    const int lbase = m0 & 1023;
    #pragma unroll
    for (int u = 0; u < 8; ++u) {
      const int gnl = wv * 32 + u * 4 + lg;
      const int gn = n0 + gnl;
      const int hh = gn >> 6, dd = gn & 63;
      const bf16x8 vvv = *reinterpret_cast<const bf16x8*>(&smem[gnl * 132 + lr * 8]);
      *reinterpret_cast<bf16x8*>(
          &ov[((size_t)(bb * H_NH + hh) * H_HD + dd) * H_S + lbase + lr * 8]) = vvv;
    }
  } else {
    #pragma unroll
    for (int j = 0; j < 4; ++j) {
      const int gn = n0 + wc * 64 + j * 16 + lr;
      const float bvl = bias[gn];
      const int hh = gn >> 6, dd = gn & 63;
      #pragma unroll
      for (int i = 0; i < 4; ++i) {
        #pragma unroll
        for (int e = 0; e < 4; ++e) {
          const int gm = m0 + wr * 64 + i * 16 + lg * 4 + e;
          const float val = acc[i][j][e] + bvl;
          const int bb = gm >> 10, ll = gm & 1023;
          if (mode == 0)   // fold 1/sqrt(64) * log2e into Q
            oq[((size_t)(bb * H_NH + hh) * H_L + ll) * H_HD + dd] = cvtbf(val * (0.125f * LOG2E));
          else
            ok_[((size_t)(bb * H_NH + hh) * H_S + ll) * H_HD + dd] = cvtbf(val);
        }
      }
    }
  }
}

// Output projection, same 2-phase dbuf structure; fp32 linear epilogue.
__global__ __launch_bounds__(256)
void out_gemm(const short* __restrict__ A, const short* __restrict__ W,
              const float* __restrict__ bias, float* __restrict__ outp)
{
  __shared__ short smem[16384];

  const int m0 = blockIdx.y * 128;
  const int n0 = blockIdx.x * 128;
  const int t = threadIdx.x;
  const int lane = t & 63;
  const int wv = t >> 6;
  const int wr = wv >> 1;
  const int wc = wv & 1;
  const int lr = lane & 15;
  const int lg = lane >> 4;

  f32x4 acc[4][4];
  const f32x4 zero = {0.f, 0.f, 0.f, 0.f};
  #pragma unroll
  for (int i = 0; i < 4; ++i)
    #pragma unroll
    for (int j = 0; j < 4; ++j) acc[i][j] = zero;

  const int g0 = wv * 2;
  const int srow = lane >> 2;
  const int scol = (lane & 3) * 8;
  const short* aptr0 = A + (size_t)(m0 + g0 * 16 + srow) * H_E + scol;
  const short* aptr1 = aptr0 + 16 * H_E;
  const short* wptr0 = W + (size_t)(n0 + g0 * 16 + srow) * H_E + scol;
  const short* wptr1 = wptr0 + 16 * H_E;

  {
    short* b = smem;
    gload16(aptr0, b + g0 * 512);
    gload16(aptr1, b + g0 * 512 + 512);
    gload16(wptr0, b + 4096 + g0 * 512);
    gload16(wptr1, b + 4096 + g0 * 512 + 512);
  }
  __syncthreads();

  int cur = 0;
  for (int kt = 0; kt < NKT; ++kt) {
    if (kt + 1 < NKT) {
      const int ko = (kt + 1) * 32;
      short* b = smem + (cur ^ 1) * 8192;
      gload16(aptr0 + ko, b + g0 * 512);
      gload16(aptr1 + ko, b + g0 * 512 + 512);
      gload16(wptr0 + ko, b + 4096 + g0 * 512);
      gload16(wptr1 + ko, b + 4096 + g0 * 512 + 512);
    }
    const short* ab = smem + cur * 8192;
    const short* wb = ab + 4096;
    bf16x8 af[4], wf[4];
    #pragma unroll
    for (int i = 0; i < 4; ++i)
      af[i] = *reinterpret_cast<const bf16x8*>(&ab[(wr * 64 + i * 16 + lr) * 32 + lg * 8]);
    #pragma unroll
    for (int j = 0; j < 4; ++j)
      wf[j] = *reinterpret_cast<const bf16x8*>(&wb[(wc * 64 + j * 16 + lr) * 32 + lg * 8]);
    #pragma unroll
    for (int i = 0; i < 4; ++i)
      #pragma unroll
      for (int j = 0; j < 4; ++j)
        acc[i][j] = __builtin_amdgcn_mfma_f32_16x16x32_bf16(af[i], wf[j], acc[i][j], 0, 0, 0);
    __syncthreads();
    cur ^= 1;
  }

  #pragma unroll
  for (int j = 0; j < 4; ++j) {
    const int gn = n0 + wc * 64 + j * 16 + lr;
    const float bvl = bias[gn];
    #pragma unroll
    for (int i = 0; i < 4; ++i) {
      #pragma unroll
      for (int e = 0; e < 4; ++e) {
        const int gm = m0 + wr * 64 + i * 16 + lg * 4 + e;
        outp[(size_t)gm * H_E + gn] = acc[i][j][e] + bvl;
      }
    }
  }
}

// Flash attention, SWAPPED QK^T (rows=s, col=q=lane&15); softmax lane-local;
// bias as MFMA C-init; exp2 domain; s_setprio around MFMA clusters.
__global__ __launch_bounds__(256)
void smha_attn(const short* __restrict__ q, const short* __restrict__ k,
               const short* __restrict__ vt, const float* __restrict__ kpm,
               const float* __restrict__ sf, short* __restrict__ outp)
{
  __shared__ short k_s[64][72];
  __shared__ short v_s[64][72];
  __shared__ short p_s[4][16][72];   // per-wave P [q][s]

  const int blk = blockIdx.x;
  const int qt = blk & 15;
  const int hh = (blk >> 4) % H_NH;
  const int bb = blk / (16 * H_NH);
  const int bh = bb * H_NH + hh;
  const int t = threadIdx.x;
  const int wv = t >> 6;
  const int lane = t & 63;
  const int lr = lane & 15;
  const int lg = lane >> 4;

  const int q0 = qt * 64 + wv * 16;

  bf16x8 qf[2];
  #pragma unroll
  for (int kk = 0; kk < 2; ++kk)
    qf[kk] = *reinterpret_cast<const bf16x8*>(
        &q[((size_t)bh * H_L + q0 + lr) * H_HD + kk * 32 + lg * 8]);

  const float sfh = sf[hh] * LOG2E;
  const float* kpmb = kpm + bb * H_S;

  f32x4 o_acc[4];
  const f32x4 zero = {0.f, 0.f, 0.f, 0.f};
  #pragma unroll
  for (int di = 0; di < 4; ++di) o_acc[di] = zero;
  float mrow = -1e30f, lrow = 0.f;

  const int srow = t >> 2;
  const int scol = (t & 3) * 16;

  const short* kp = &k[((size_t)bh * H_S + srow) * H_HD + scol];
  const short* vp = &vt[((size_t)bh * H_HD + srow) * H_S + scol];
  bf16x8 kr0 = *reinterpret_cast<const bf16x8*>(kp);
  bf16x8 kr1 = *reinterpret_cast<const bf16x8*>(kp + 8);
  bf16x8 vr0 = *reinterpret_cast<const bf16x8*>(vp);
  bf16x8 vr1 = *reinterpret_cast<const bf16x8*>(vp + 8);

  for (int kv = 0; kv < H_S / 64; ++kv) {
    const int s0 = kv * 64;
    __syncthreads();
    *reinterpret_cast<bf16x8*>(&k_s[srow][scol])     = kr0;
    *reinterpret_cast<bf16x8*>(&k_s[srow][scol + 8]) = kr1;
    *reinterpret_cast<bf16x8*>(&v_s[srow][scol])     = vr0;
    *reinterpret_cast<bf16x8*>(&v_s[srow][scol + 8]) = vr1;
    __syncthreads();
    if (kv + 1 < H_S / 64) {
      const short* kpn = kp + (size_t)(kv + 1) * 64 * H_HD;
      const short* vpn = vp + (size_t)(kv + 1) * 64;
      kr0 = *reinterpret_cast<const bf16x8*>(kpn);
      kr1 = *reinterpret_cast<const bf16x8*>(kpn + 8);
      vr0 = *reinterpret_cast<const bf16x8*>(vpn);
      vr1 = *reinterpret_cast<const bf16x8*>(vpn + 8);
    }

    // S^T = K Q^T + bias (C-init: rows = s)
    f32x4 sc[4];
    #pragma unroll
    for (int ni = 0; ni < 4; ++ni) {
      const f32x4 kp4 = *reinterpret_cast<const f32x4*>(&kpmb[s0 + ni * 16 + lg * 4]);
      #pragma unroll
      for (int e = 0; e < 4; ++e) sc[ni][e] = kp4[e] * sfh;
    }
    __builtin_amdgcn_s_setprio(1);
    #pragma unroll
    for (int kk = 0; kk < 2; ++kk) {
      #pragma unroll
      for (int ni = 0; ni < 4; ++ni) {
        const bf16x8 kf = *reinterpret_cast<const bf16x8*>(&k_s[ni * 16 + lr][kk * 32 + lg * 8]);
        sc[ni] = __builtin_amdgcn_mfma_f32_16x16x32_bf16(kf, qf[kk], sc[ni], 0, 0, 0);
      }
    }
    __builtin_amdgcn_s_setprio(0);

    float pm[4];
    #pragma unroll
    for (int ni = 0; ni < 4; ++ni)
      pm[ni] = fmaxf(fmaxf(sc[ni][0], sc[ni][1]), fmaxf(sc[ni][2], sc[ni][3]));
    float mx = fmaxf(fmaxf(pm[0], pm[1]), fmaxf(pm[2], pm[3]));
    mx = fmaxf(mx, __shfl_xor(mx, 16));
    mx = fmaxf(mx, __shfl_xor(mx, 32));

    if (!__all(mx <= mrow + 11.5f)) {
      const float mnew = fmaxf(mrow, mx);
      const float scal = fexp2(mrow - mnew);
      lrow *= scal;
      float sj[4];
      #pragma unroll
      for (int j = 0; j < 4; ++j) sj[j] = __shfl(scal, lg * 4 + j);
      #pragma unroll
      for (int di = 0; di < 4; ++di)
        #pragma unroll
        for (int j = 0; j < 4; ++j) o_acc[di][j] *= sj[j];
      mrow = mnew;
    }

    float ps[4];
    #pragma unroll
    for (int ni = 0; ni < 4; ++ni) {
      #pragma unroll
      for (int e = 0; e < 4; ++e) sc[ni][e] = fexp2(sc[ni][e] - mrow);
      ps[ni] = (sc[ni][0] + sc[ni][1]) + (sc[ni][2] + sc[ni][3]);
    }
    float rs = (ps[0] + ps[1]) + (ps[2] + ps[3]);
    rs += __shfl_xor(rs, 16);
    rs += __shfl_xor(rs, 32);
    lrow += rs;

    #pragma unroll
    for (int ni = 0; ni < 4; ++ni) {
      bf16x4 pk4;
      pk4[0] = cvtbf(sc[ni][0]); pk4[1] = cvtbf(sc[ni][1]);
      pk4[2] = cvtbf(sc[ni][2]); pk4[3] = cvtbf(sc[ni][3]);
      *reinterpret_cast<bf16x4*>(&p_s[wv][lr][ni * 16 + lg * 4]) = pk4;
    }

    __builtin_amdgcn_s_setprio(1);
    #pragma unroll
    for (int kk = 0; kk < 2; ++kk) {
      const bf16x8 pf = *reinterpret_cast<const bf16x8*>(&p_s[wv][lr][kk * 32 + lg * 8]);
      #pragma unroll
      for (int di = 0; di < 4; ++di) {
        const bf16x8 vfr = *reinterpret_cast<const bf16x8*>(&v_s[di * 16 + lr][kk * 32 + lg * 8]);
        o_acc[di] = __builtin_amdgcn_mfma_f32_16x16x32_bf16(pf, vfr, o_acc[di], 0, 0, 0);
      }
    }
    __builtin_amdgcn_s_setprio(0);
  }

  #pragma unroll
  for (int j = 0; j < 4; ++j) {
    const float rl = 1.0f / __shfl(lrow, lg * 4 + j);
    const int gq = q0 + lg * 4 + j;
    #pragma unroll
    for (int di = 0; di < 4; ++di)
      outp[((size_t)bb * H_L + gq) * H_E + hh * H_HD + di * 16 + lr] =
          cvtbf(o_acc[di][j] * rl);
  }
}

extern "C" void kernel_launch(void* const* d_in, const int* in_sizes, int n_in,
                              void* d_out, int out_size, void* d_ws, size_t ws_size,
                              hipStream_t stream)
{
  // 0 query, 1 key, 2 value, 3 kpm, 4 Wq, 5 bq, 6 Wk, 7 bk, 8 Wv, 9 bv,
  // 10 Wo, 11 bo, 12 scaling_factors
  short* ws_w  = (short*)d_ws;                    // 4*EE bf16 weights
  short* ws_a  = ws_w + (size_t)4 * EE;           // 3*AN bf16 activations
  short* ws_q  = ws_a + (size_t)3 * AN;
  short* ws_k  = ws_q + AN;
  short* ws_vt = ws_k + AN;
  short* ws_at = ws_a;                            // alias: ws_a dead after qkv_gemm

  conv_bf16<<<dim3(AN / 2048, 7), 256, 0, stream>>>(
      (const float*)d_in[4], (const float*)d_in[6], (const float*)d_in[8],
      (const float*)d_in[10], (const float*)d_in[0], (const float*)d_in[1],
      (const float*)d_in[2], ws_w, ws_a);

  qkv_gemm<<<dim3(H_E / 128, (H_BS * H_L) / 128, 3), 256, 0, stream>>>(
      ws_a, ws_w, (const float*)d_in[5], (const float*)d_in[7],
      (const float*)d_in[9], ws_q, ws_k, ws_vt);

  smha_attn<<<H_BS * H_NH * (H_L / 64), 256, 0, stream>>>(
      ws_q, ws_k, ws_vt, (const float*)d_in[3], (const float*)d_in[12], ws_at);

  out_gemm<<<dim3(H_E / 128, (H_BS * H_L) / 128), 256, 0, stream>>>(
      ws_at, ws_w + (size_t)3 * EE, (const float*)d_in[11], (float*)d_out);
}